// Round 3
// baseline (311.775 us; speedup 1.0000x reference)
//
#include <hip/hip_runtime.h>
#include <hip/hip_bf16.h>
#include <stdint.h>

#define T_SEQ 4096
#define C_DIM 2048
#define H_DIM 128
#define NBATCH 4

typedef unsigned short u16;
typedef __attribute__((ext_vector_type(8))) __bf16 bf16x8;
typedef __attribute__((ext_vector_type(4))) float f32x4;
typedef __attribute__((ext_vector_type(8))) unsigned short u16x8;
typedef __attribute__((ext_vector_type(4))) unsigned short u16x4;

__device__ __forceinline__ u16 f2bf(float f) {
  union { float f; uint32_t i; } v; v.f = f;
  uint32_t r = v.i + 0x7FFFu + ((v.i >> 16) & 1u);
  return (u16)(r >> 16);
}
__device__ __forceinline__ float bf2f(u16 u) {
  union { uint32_t i; float f; } v; v.i = ((uint32_t)u) << 16;
  return v.f;
}

__device__ __forceinline__ void gload16(const void* g, void* l) {
  __builtin_amdgcn_global_load_lds(
      (__attribute__((address_space(1))) void*)(g),
      (__attribute__((address_space(3))) void*)(l), 16, 0, 0);
}

__device__ __forceinline__ f32x4 mfma_bf16(bf16x8 a, bf16x8 b, f32x4 c) {
  return __builtin_amdgcn_mfma_f32_16x16x32_bf16(a, b, c, 0, 0, 0);
}

// DPP row rotate (16-lane row) reductions — no LDS traffic.
template<int CTRL>
__device__ __forceinline__ float dpp_mov(float x) {
  return __int_as_float(__builtin_amdgcn_mov_dpp(__float_as_int(x), CTRL, 0xF, 0xF, true));
}
__device__ __forceinline__ float red16_max(float v) {
  v = fmaxf(v, dpp_mov<0x121>(v));
  v = fmaxf(v, dpp_mov<0x122>(v));
  v = fmaxf(v, dpp_mov<0x124>(v));
  v = fmaxf(v, dpp_mov<0x128>(v));
  return v;
}
__device__ __forceinline__ float red16_sum(float v) {
  v += dpp_mov<0x121>(v);
  v += dpp_mov<0x122>(v);
  v += dpp_mov<0x124>(v);
  v += dpp_mov<0x128>(v);
  return v;
}

// ---------------------------------------------------------------------------
// Kernel 1: W fp32 [2048][128] -> Wt bf16 [p][n][k], pre-swizzled so that
// contiguous global_load_lds staging lands an XOR-swizzled B-tile in LDS.
// (unchanged, verified in prior session)
// ---------------------------------------------------------------------------
__global__ __launch_bounds__(256) void transpose_w(
    const float* __restrict__ Wq, const float* __restrict__ Wk,
    const float* __restrict__ Wv, u16* __restrict__ Wt)
{
  __shared__ u16 Wl[64 * 72];
  const int bk = blockIdx.x;   // k-tile 0..31
  const int bn = blockIdx.y;   // n-tile 0..1
  const int p  = blockIdx.z;   // 0 q, 1 k, 2 v
  const float* W = (p == 0) ? Wq : (p == 1) ? Wk : Wv;
  const int t = threadIdx.x;

  for (int ps = 0; ps < 16; ++ps) {
    int e  = ps * 256 + t;
    int kk = e >> 6, nn = e & 63;
    Wl[kk * 72 + nn] = f2bf(W[(size_t)(bk * 64 + kk) * H_DIM + bn * 64 + nn]);
  }
  __syncthreads();
  for (int ps = 0; ps < 16; ++ps) {
    int o  = ps * 256 + t;
    int nl = o >> 6, kl = o & 63;
    int n  = bn * 64 + nl;
    int g  = kl >> 3, j = kl & 7;
    int ks = ((g ^ (n & 7)) << 3) | j;
    Wt[(size_t)p * (H_DIM * C_DIM) + (size_t)n * C_DIM + bk * 64 + kl] = Wl[ks * 72 + nl];
  }
}

// ---------------------------------------------------------------------------
// Kernel 2: FUSED QKV GEMM (unchanged — HBM-bound control).
// ---------------------------------------------------------------------------
__global__ __launch_bounds__(512, 1) void qkv_fused(
    const float* __restrict__ x, const u16* __restrict__ Wt,
    const float* __restrict__ bq, const float* __restrict__ bk, const float* __restrict__ bv,
    u16* __restrict__ qo, u16* __restrict__ ko, u16* __restrict__ vTo)
{
  __shared__ alignas(16) u16 SMEM[2][28672];   // 2 x (As 8KB | Bs 48KB) = 112 KB

  const int tid  = threadIdx.x;
  const int w    = tid >> 6, lane = tid & 63;
  const int t16  = lane & 15, quad = lane >> 4;
  const int mh   = w >> 2;        // m-half: rows mh*32..+32
  const int nq   = w & 3;         // n-strip: cols nq*96..+96
  const int rt   = blockIdx.x;    // 0..255 row tiles (64 rows each)

  f32x4 acc[2][6];
  for (int i = 0; i < 2; ++i)
    for (int j = 0; j < 6; ++j) acc[i][j] = f32x4{0.f, 0.f, 0.f, 0.f};

  const size_t rowBase = (size_t)rt * 64;
  const int arow = tid >> 3;      // 0..63
  const int ag   = tid & 7;       // 8-float granule
  const float* xrow = &x[(rowBase + arow) * C_DIM + ag * 8];

  float4 a0 = ((const float4*)(xrow))[0];
  float4 a1 = ((const float4*)(xrow))[1];
  {
    u16* As = SMEM[0];
    u16* Bs = SMEM[0] + 4096;
    for (int p = 0; p < 3; ++p) {
      const u16* Wp = Wt + (size_t)p * (H_DIM * C_DIM);
      for (int j = 0; j < 2; ++j) {
        int e8 = (((j << 3) + w) * 64 + lane) * 8;
        int rr = e8 >> 6, kk = e8 & 63;
        gload16(Wp + (size_t)rr * C_DIM + kk, &Bs[p * 8192 + e8]);
      }
    }
    u16x8 pk;
    pk[0] = f2bf(a0.x); pk[1] = f2bf(a0.y); pk[2] = f2bf(a0.z); pk[3] = f2bf(a0.w);
    pk[4] = f2bf(a1.x); pk[5] = f2bf(a1.y); pk[6] = f2bf(a1.z); pk[7] = f2bf(a1.w);
    *(u16x8*)&As[arow * 64 + ((ag ^ (arow & 7)) << 3)] = pk;
  }
  a0 = ((const float4*)(xrow + 64))[0];
  a1 = ((const float4*)(xrow + 64))[1];

  for (int it = 0; it < 32; ++it) {
    const int cur = it & 1, nxt = cur ^ 1;
    __syncthreads();

    if (it + 1 < 32) {
      const int k1 = (it + 1) * 64;
      u16* As = SMEM[nxt];
      u16* Bs = SMEM[nxt] + 4096;
      for (int p = 0; p < 3; ++p) {
        const u16* Wp = Wt + (size_t)p * (H_DIM * C_DIM);
        for (int j = 0; j < 2; ++j) {
          int e8 = (((j << 3) + w) * 64 + lane) * 8;
          int rr = e8 >> 6, kk = e8 & 63;
          gload16(Wp + (size_t)rr * C_DIM + k1 + kk, &Bs[p * 8192 + e8]);
        }
      }
      u16x8 pk;
      pk[0] = f2bf(a0.x); pk[1] = f2bf(a0.y); pk[2] = f2bf(a0.z); pk[3] = f2bf(a0.w);
      pk[4] = f2bf(a1.x); pk[5] = f2bf(a1.y); pk[6] = f2bf(a1.z); pk[7] = f2bf(a1.w);
      *(u16x8*)&As[arow * 64 + ((ag ^ (arow & 7)) << 3)] = pk;
      if (it + 2 < 32) {
        const float4* xp = (const float4*)(xrow + (it + 2) * 64);
        a0 = xp[0]; a1 = xp[1];
      }
    }

    u16* As = SMEM[cur];
    u16* Bs = SMEM[cur] + 4096;
    for (int ks = 0; ks < 2; ++ks) {
      bf16x8 af[2], bfr[6];
      for (int ra = 0; ra < 2; ++ra)
        af[ra] = *(const bf16x8*)&As[(mh * 32 + ra * 16 + t16) * 64 +
                                     (((ks * 4 + quad) ^ (t16 & 7)) << 3)];
      for (int c = 0; c < 6; ++c) {
        int col = nq * 96 + c * 16 + t16;
        int p = col >> 7, pc = col & 127;
        bfr[c] = *(const bf16x8*)&Bs[p * 8192 + pc * 64 +
                                     (((ks * 4 + quad) ^ (t16 & 7)) << 3)];
      }
      for (int ra = 0; ra < 2; ++ra)
        for (int c = 0; c < 6; ++c)
          acc[ra][c] = mfma_bf16(af[ra], bfr[c], acc[ra][c]);
    }
  }

  __syncthreads();
  u16* Oq = SMEM[0];            // 64 x 128 row-major swizzled
  u16* Ok = SMEM[0] + 8192;     // 64 x 128 row-major swizzled (== global layout)
  u16* Ov = SMEM[0] + 16384;    // 128 x 64 transposed swizzled (== global layout)

  for (int c = 0; c < 6; ++c) {
    int col = nq * 96 + c * 16 + t16;
    int p = col >> 7, pc = col & 127;
    float bias = (p == 0) ? bq[pc] : (p == 1) ? bk[pc] : bv[pc];
    for (int ra = 0; ra < 2; ++ra) {
      for (int r = 0; r < 4; ++r) {
        int row16 = mh * 32 + ra * 16 + quad * 4 + r;   // 0..63
        float v = acc[ra][c][r] + bias;
        if (p == 2) {
          int gt = row16 >> 3;
          Ov[pc * 64 + ((gt ^ (pc & 7)) << 3) + (row16 & 7)] = f2bf(v);
        } else {
          u16* O = (p == 0) ? Oq : Ok;
          int g = pc >> 3;
          O[row16 * 128 + (((g ^ (row16 & 15)) << 3) | (pc & 7))] = f2bf(v);
        }
      }
    }
  }
  __syncthreads();

  const int bb = rt >> 6;            // batch
  const int tb = (rt & 63) * 64;     // t offset within batch (one key-block)
  for (int ps = 0; ps < 2; ++ps) {
    int c = ps * 512 + tid;          // 16B chunk 0..1023
    {
      int row16 = c >> 4, g = c & 15;
      u16x8 v = *(const u16x8*)&Oq[row16 * 128 + ((g ^ (row16 & 15)) << 3)];
      *(u16x8*)&qo[(rowBase + row16) * H_DIM + g * 8] = v;
    }
    *(u16x8*)&ko[rowBase * H_DIM + c * 8] = *(const u16x8*)&Ok[c * 8];
    {
      int d = c >> 3, gc = c & 7;
      *(u16x8*)&vTo[((size_t)bb * H_DIM + d) * T_SEQ + tb + gc * 8] =
          *(const u16x8*)&Ov[c * 8];
    }
  }
}

// ---------------------------------------------------------------------------
// Kernel 3: causal flash attention — 128-row q-tiles, 4 waves x 32 rows.
// Per-wave K/V LDS reads (16+16 b128/iter) amortize over 32 rows (was 16).
// BALANCED SPLIT: chunks of <=16 key-tiles, nchunks(qt) in {1,2,3,4};
// 80 chunks/batch -> 320 blocks, all co-resident at 2 blocks/CU (LDS 80KB).
// Chunk 0 -> unnormalized fp32 in `out`; chunks >=1 -> partials in Opart,
// fp32 if workspace allows (pf32=1) else bf16. Mask-safety: chunk's first
// tile kt0 <= 2qt always (n <= qt+1), so every row sees an unmasked key
// before any fully-masked tile -> no exp2(0) poisoning.
// ---------------------------------------------------------------------------
__global__ __launch_bounds__(256, 2) void flash_attn(
    const u16* __restrict__ q, const u16* __restrict__ k,
    const u16* __restrict__ vT, float* __restrict__ out,
    void* __restrict__ OpartRaw, float* __restrict__ MLpart,
    int split, int pf32)
{
  __shared__ alignas(16) u16 Kt[2][64 * 128];   // 2 x 16 KB
  __shared__ alignas(16) u16 Vt[2][128 * 64];   // 2 x 16 KB
  __shared__ alignas(16) u16 Ps[4][32 * 64];    // 16 KB, XOR-swizzled

  const int tid  = threadIdx.x;
  const int w    = tid >> 6, lane = tid & 63;
  const int t16  = lane & 15, quad = lane >> 4;
  const int b    = blockIdx.x;

  // ---- schedule: (qt, chunk) from blockIdx.y ----
  int qt, kt0, ktn, mls, esd;   // mls<0 => direct; esd==-2 => chunk0 -> out
  if (split) {
    const int j = blockIdx.y;   // 0..79
    int cidx, n;
    if (j < 32)      { qt = 31 - (j >> 2); cidx = j & 3; n = 4; }
    else if (j < 56) { int t = j - 32; int d3 = t / 3; qt = 23 - d3; cidx = t - d3 * 3; n = 3; }
    else if (j < 72) { int t = j - 56; qt = 15 - (t >> 1); cidx = t & 1; n = 2; }
    else             { qt = 79 - j; cidx = 0; n = 1; }
    const int NT = 2 * qt + 2;
    kt0 = cidx * NT / n;
    ktn = (cidx + 1) * NT / n - kt0;
    if (n == 1) { mls = -1; esd = -1; }
    else {
      int mlb, esb;
      if (qt >= 24)      { mlb = (qt - 24) * 4;      esb = (qt - 24) * 3; }
      else if (qt >= 16) { mlb = 32 + (qt - 16) * 3; esb = 24 + (qt - 16) * 2; }
      else               { mlb = 56 + (qt - 8) * 2;  esb = 40 + (qt - 8); }
      mls = b * 72 + mlb + cidx;
      esd = (cidx >= 1) ? (b * 48 + esb + cidx - 1) : -2;
    }
  } else {
    qt = 31 - blockIdx.y; kt0 = 0; ktn = 2 * qt + 2; mls = -1; esd = -1;
  }

  const float SCALE = 0.022097086912079612f;   // 2048^-0.5
  const float L2E   = 1.4426950408889634f;

  bf16x8 qf[2][4];
  for (int rh = 0; rh < 2; ++rh) {
    const u16* qrow = q + ((size_t)(b * T_SEQ + qt * 128 + w * 32 + rh * 16 + t16)) * H_DIM;
    for (int c = 0; c < 4; ++c)
      qf[rh][c] = *(const bf16x8*)(qrow + c * 32 + quad * 8);
  }

  f32x4 Oc[2][8];
  for (int rh = 0; rh < 2; ++rh)
    for (int i = 0; i < 8; ++i) Oc[rh][i] = f32x4{0.f, 0.f, 0.f, 0.f};
  float mrow[2][4], lrow[2][4];
  for (int rh = 0; rh < 2; ++rh)
    for (int r = 0; r < 4; ++r) { mrow[rh][r] = -1e30f; lrow[rh][r] = 0.f; }

  const u16* kbase = k  + ((size_t)b * T_SEQ) * H_DIM;
  const u16* vbase = vT + ((size_t)b * H_DIM) * T_SEQ;

  // prefetch first tile into buffer 0
  {
    const u16* kg = kbase + (size_t)(kt0 * 64) * H_DIM;
    for (int j = 0; j < 4; ++j) {
      int e8 = (((j << 2) + w) * 64 + lane) * 8;
      gload16(kg + e8, &Kt[0][e8]);
      int d = e8 >> 6, kk = e8 & 63;
      gload16(vbase + (size_t)d * T_SEQ + kt0 * 64 + kk, &Vt[0][e8]);
    }
  }

  int cur = 0;
  for (int it = 0; it < ktn; ++it) {
    const int kt = kt0 + it;
    __syncthreads();   // drains prefetch of `cur`; WAR-guard for next prefetch
    if (it + 1 < ktn) {
      const int nb = cur ^ 1, kt1 = kt + 1;
      const u16* kg = kbase + (size_t)(kt1 * 64) * H_DIM;
      for (int j = 0; j < 4; ++j) {
        int e8 = (((j << 2) + w) * 64 + lane) * 8;
        gload16(kg + e8, &Kt[nb][e8]);
        int d = e8 >> 6, kk = e8 & 63;
        gload16(vbase + (size_t)d * T_SEQ + kt1 * 64 + kk, &Vt[nb][e8]);
      }
    }

    // S = Q K^T  — kf read once, used by both row-halves
    f32x4 S[2][4];
    for (int rh = 0; rh < 2; ++rh)
      for (int ct = 0; ct < 4; ++ct) S[rh][ct] = f32x4{0.f, 0.f, 0.f, 0.f};

    __builtin_amdgcn_s_setprio(1);
    for (int c = 0; c < 4; ++c)
      for (int ct = 0; ct < 4; ++ct) {
        bf16x8 kf = *(const bf16x8*)&Kt[cur][(ct * 16 + t16) * H_DIM +
                                            (((c * 4 + quad) ^ t16) << 3)];
        S[0][ct] = mfma_bf16(qf[0][c], kf, S[0][ct]);
        S[1][ct] = mfma_bf16(qf[1][c], kf, S[1][ct]);
      }
    __builtin_amdgcn_s_setprio(0);

    const int kb0 = kt * 64;
    for (int rh = 0; rh < 2; ++rh) {
      const int r0 = qt * 128 + w * 32 + rh * 16;   // global q-row of tile row 0
      const bool needmask = (kb0 + 63 > r0);
      for (int ct = 0; ct < 4; ++ct)
        for (int r = 0; r < 4; ++r) {
          float s = S[rh][ct][r] * SCALE;
          if (needmask && (kb0 + ct * 16 + t16 > r0 + quad * 4 + r)) s = -1e30f;
          S[rh][ct][r] = s;
        }
    }

    float alpha[2][4];
    for (int rh = 0; rh < 2; ++rh)
      for (int r = 0; r < 4; ++r) {
        float mx = red16_max(fmaxf(fmaxf(S[rh][0][r], S[rh][1][r]),
                                   fmaxf(S[rh][2][r], S[rh][3][r])));
        float mn = fmaxf(mrow[rh][r], mx);
        alpha[rh][r] = exp2f((mrow[rh][r] - mn) * L2E);
        mrow[rh][r] = mn;
        float ssum = 0.f;
        for (int ct = 0; ct < 4; ++ct) {
          float pv = exp2f((S[rh][ct][r] - mn) * L2E);
          S[rh][ct][r] = pv;
          ssum += pv;
        }
        lrow[rh][r] = lrow[rh][r] * alpha[rh][r] + red16_sum(ssum);
      }
    for (int rh = 0; rh < 2; ++rh)
      for (int dt = 0; dt < 8; ++dt)
        for (int r = 0; r < 4; ++r)
          Oc[rh][dt][r] *= alpha[rh][r];

    // P: C layout -> A layout via per-wave XOR-swizzled LDS scratch (32x64)
    u16* pw = Ps[w];
    for (int rh = 0; rh < 2; ++rh)
      for (int ct = 0; ct < 4; ++ct)
        for (int r = 0; r < 4; ++r) {
          int row = rh * 16 + quad * 4 + r;
          pw[row * 64 + ((((ct << 1) | (t16 >> 3)) ^ (row & 7)) << 3) + (t16 & 7)]
              = f2bf(S[rh][ct][r]);
        }
    __asm__ volatile("s_waitcnt lgkmcnt(0)" ::: "memory");

    __builtin_amdgcn_s_setprio(1);
    for (int ks = 0; ks < 2; ++ks) {
      bf16x8 pf0 = *(const bf16x8*)&pw[t16 * 64 + (((ks * 4 + quad) ^ (t16 & 7)) << 3)];
      bf16x8 pf1 = *(const bf16x8*)&pw[(16 + t16) * 64 + (((ks * 4 + quad) ^ (t16 & 7)) << 3)];
      for (int dt = 0; dt < 8; ++dt) {
        bf16x8 vf = *(const bf16x8*)&Vt[cur][(dt * 16 + t16) * 64 +
                                            (((ks * 4 + quad) ^ (t16 & 7)) << 3)];
        Oc[0][dt] = mfma_bf16(pf0, vf, Oc[0][dt]);
        Oc[1][dt] = mfma_bf16(pf1, vf, Oc[1][dt]);
      }
    }
    __builtin_amdgcn_s_setprio(0);
    cur ^= 1;
  }

  if (mls < 0) {
    for (int rh = 0; rh < 2; ++rh)
      for (int r = 0; r < 4; ++r) {
        float inv = 1.0f / lrow[rh][r];
        size_t row = (size_t)b * T_SEQ + qt * 128 + w * 32 + rh * 16 + quad * 4 + r;
        for (int dt = 0; dt < 8; ++dt)
          out[row * H_DIM + dt * 16 + t16] = Oc[rh][dt][r] * inv;
      }
  } else {
    if (t16 == 0)
      for (int rh = 0; rh < 2; ++rh)
        for (int r = 0; r < 4; ++r) {
          int row = w * 32 + rh * 16 + quad * 4 + r;
          MLpart[(size_t)mls * 256 + row * 2 + 0] = mrow[rh][r];
          MLpart[(size_t)mls * 256 + row * 2 + 1] = lrow[rh][r];
        }
    if (esd == -2) {
      // chunk 0: unnormalized partial straight into out (combine rescales)
      for (int rh = 0; rh < 2; ++rh)
        for (int r = 0; r < 4; ++r) {
          size_t row = (size_t)b * T_SEQ + qt * 128 + w * 32 + rh * 16 + quad * 4 + r;
          for (int dt = 0; dt < 8; ++dt)
            out[row * H_DIM + dt * 16 + t16] = Oc[rh][dt][r];
        }
    } else if (pf32) {
      float* op = (float*)OpartRaw + (size_t)esd * 16384;
      for (int rh = 0; rh < 2; ++rh)
        for (int r = 0; r < 4; ++r) {
          int row = w * 32 + rh * 16 + quad * 4 + r;
          for (int dt = 0; dt < 8; ++dt)
            op[row * 128 + dt * 16 + t16] = Oc[rh][dt][r];
        }
    } else {
      u16* op = (u16*)OpartRaw + (size_t)esd * 16384;
      for (int rh = 0; rh < 2; ++rh)
        for (int r = 0; r < 4; ++r) {
          int row = w * 32 + rh * 16 + quad * 4 + r;
          for (int dt = 0; dt < 8; ++dt)
            op[row * 128 + dt * 16 + t16] = f2bf(Oc[rh][dt][r]);
        }
    }
  }
}

// ---------------------------------------------------------------------------
// Kernel 4: merge chunk 0 (in out, unnormalized fp32) with chunks 1..n-1
// (Opart, fp32 or bf16). One block per split (b,qt); n in {2,3,4}.
// ---------------------------------------------------------------------------
__global__ __launch_bounds__(256) void combine(
    const void* __restrict__ OpartRaw, const float* __restrict__ MLpart,
    float* __restrict__ out, int pf32)
{
  __shared__ float cs[4][128];
  const float L2E = 1.4426950408889634f;
  const int s = blockIdx.x;            // 0..95
  const int b = s / 24, qt = 8 + (s % 24);
  const int t = threadIdx.x;

  int n, mlb, esb;
  if (qt >= 24)      { n = 4; mlb = (qt - 24) * 4;      esb = (qt - 24) * 3; }
  else if (qt >= 16) { n = 3; mlb = 32 + (qt - 16) * 3; esb = 24 + (qt - 16) * 2; }
  else               { n = 2; mlb = 56 + (qt - 8) * 2;  esb = 40 + (qt - 8); }
  const int mls0 = b * 72 + mlb;
  const int esd0 = b * 48 + esb;

  if (t < 128) {
    float m[4], l[4];
    float mg = -1e30f;
    for (int c = 0; c < n; ++c) {
      const float* ML = MLpart + (size_t)(mls0 + c) * 256;
      m[c] = ML[t * 2]; l[c] = ML[t * 2 + 1];
      mg = fmaxf(mg, m[c]);
    }
    float denom = 0.f, e[4];
    for (int c = 0; c < n; ++c) {
      e[c] = exp2f((m[c] - mg) * L2E);
      denom += l[c] * e[c];
    }
    float inv = 1.0f / denom;
    for (int c = 0; c < n; ++c) cs[c][t] = e[c] * inv;
  }
  __syncthreads();

  float* o = out + ((size_t)b * T_SEQ + (size_t)qt * 128) * (size_t)H_DIM;
  for (int i4 = t; i4 < 4096; i4 += 256) {       // float4 chunks, 32 per row
    const int row = i4 >> 5;
    float4 acc = ((float4*)o)[i4];
    const float c0 = cs[0][row];
    acc.x *= c0; acc.y *= c0; acc.z *= c0; acc.w *= c0;
    for (int c = 1; c < n; ++c) {
      const float cc = cs[c][row];
      if (pf32) {
        const float4 p = ((const float4*)((const float*)OpartRaw +
                          (size_t)(esd0 + c - 1) * 16384))[i4];
        acc.x += p.x * cc; acc.y += p.y * cc;
        acc.z += p.z * cc; acc.w += p.w * cc;
      } else {
        const u16x4 p = ((const u16x4*)((const u16*)OpartRaw +
                         (size_t)(esd0 + c - 1) * 16384))[i4];
        acc.x += bf2f(p[0]) * cc; acc.y += bf2f(p[1]) * cc;
        acc.z += bf2f(p[2]) * cc; acc.w += bf2f(p[3]) * cc;
      }
    }
    ((float4*)o)[i4] = acc;
  }
}

// ---------------------------------------------------------------------------
extern "C" void kernel_launch(void* const* d_in, const int* in_sizes, int n_in,
                              void* d_out, int out_size, void* d_ws, size_t ws_size,
                              hipStream_t stream) {
  const float* x  = (const float*)d_in[0];
  const float* Wk = (const float*)d_in[1];
  const float* bk = (const float*)d_in[2];
  const float* Wq = (const float*)d_in[3];
  const float* bq = (const float*)d_in[4];
  const float* Wv = (const float*)d_in[5];
  const float* bv = (const float*)d_in[6];
  float* out = (float*)d_out;

  char* ws = (char*)d_ws;
  u16* qb  = (u16*)(ws);                       // 4 MB  [b][t][128] bf16
  u16* kb  = (u16*)(ws + 4194304);             // 4 MB  [b][t][d'] bf16 (swizzled)
  u16* vT  = (u16*)(ws + 8388608);             // 4 MB  [b][128][t'] bf16 (swizzled)
  u16* Wt  = (u16*)(ws + 12582912);            // 1.5 MB pre-swizzled weights
  void* Opart = (void*)(ws + 14155776);        // partials: 192 slots of 128x128

  const size_t base     = 14155776ull;
  const size_t ml_bytes = 294912ull;           // 288 slots x 256 f32
  const size_t need_f32 = base + 12582912ull + ml_bytes;   // fp32 partials
  const size_t need_b16 = base + 6291456ull  + ml_bytes;   // bf16 partials

  int split, pf32;
  float* MLpart;
  if (ws_size >= need_f32) {
    split = 1; pf32 = 1;
    MLpart = (float*)(ws + base + 12582912ull);
  } else if (ws_size >= need_b16) {
    split = 1; pf32 = 0;
    MLpart = (float*)(ws + base + 6291456ull);
  } else {
    split = 0; pf32 = 0;
    MLpart = (float*)(ws + base);              // unused
  }

  hipLaunchKernelGGL(transpose_w, dim3(32, 2, 3), dim3(256), 0, stream, Wq, Wk, Wv, Wt);
  hipLaunchKernelGGL(qkv_fused, dim3(256), dim3(512), 0, stream,
                     x, Wt, bq, bk, bv, qb, kb, vT);
  hipLaunchKernelGGL(flash_attn, dim3(4, split ? 80 : 32), dim3(256), 0, stream,
                     qb, kb, vT, out, Opart, MLpart, split, pf32);
  if (split)
    hipLaunchKernelGGL(combine, dim3(96), dim3(256), 0, stream, Opart, MLpart, out, pf32);
}

// Round 6
// 299.119 us; speedup vs baseline: 1.0423x; 1.0423x over previous
//
#include <hip/hip_runtime.h>
#include <hip/hip_bf16.h>
#include <stdint.h>

#define T_SEQ 4096
#define C_DIM 2048
#define H_DIM 128
#define NBATCH 4

typedef unsigned short u16;
typedef __attribute__((ext_vector_type(8))) __bf16 bf16x8;
typedef __attribute__((ext_vector_type(4))) float f32x4;
typedef __attribute__((ext_vector_type(8))) unsigned short u16x8;
typedef __attribute__((ext_vector_type(4))) unsigned short u16x4;

__device__ __forceinline__ u16 f2bf(float f) {
  union { float f; uint32_t i; } v; v.f = f;
  uint32_t r = v.i + 0x7FFFu + ((v.i >> 16) & 1u);
  return (u16)(r >> 16);
}
__device__ __forceinline__ float bf2f(u16 u) {
  union { uint32_t i; float f; } v; v.i = ((uint32_t)u) << 16;
  return v.f;
}

__device__ __forceinline__ void gload16(const void* g, void* l) {
  __builtin_amdgcn_global_load_lds(
      (__attribute__((address_space(1))) void*)(g),
      (__attribute__((address_space(3))) void*)(l), 16, 0, 0);
}

__device__ __forceinline__ f32x4 mfma_bf16(bf16x8 a, bf16x8 b, f32x4 c) {
  return __builtin_amdgcn_mfma_f32_16x16x32_bf16(a, b, c, 0, 0, 0);
}

// DPP row rotate (16-lane row) reductions — no LDS traffic.
template<int CTRL>
__device__ __forceinline__ float dpp_mov(float x) {
  return __int_as_float(__builtin_amdgcn_mov_dpp(__float_as_int(x), CTRL, 0xF, 0xF, true));
}
__device__ __forceinline__ float red16_max(float v) {
  v = fmaxf(v, dpp_mov<0x121>(v));
  v = fmaxf(v, dpp_mov<0x122>(v));
  v = fmaxf(v, dpp_mov<0x124>(v));
  v = fmaxf(v, dpp_mov<0x128>(v));
  return v;
}
__device__ __forceinline__ float red16_sum(float v) {
  v += dpp_mov<0x121>(v);
  v += dpp_mov<0x122>(v);
  v += dpp_mov<0x124>(v);
  v += dpp_mov<0x128>(v);
  return v;
}

// ---------------------------------------------------------------------------
// Kernel 1: W fp32 [2048][128] -> Wt bf16 [p][n][k], pre-swizzled so that
// contiguous global_load_lds staging lands an XOR-swizzled B-tile in LDS.
// (unchanged, session-verified)
// ---------------------------------------------------------------------------
__global__ __launch_bounds__(256) void transpose_w(
    const float* __restrict__ Wq, const float* __restrict__ Wk,
    const float* __restrict__ Wv, u16* __restrict__ Wt)
{
  __shared__ u16 Wl[64 * 72];
  const int bk = blockIdx.x;   // k-tile 0..31
  const int bn = blockIdx.y;   // n-tile 0..1
  const int p  = blockIdx.z;   // 0 q, 1 k, 2 v
  const float* W = (p == 0) ? Wq : (p == 1) ? Wk : Wv;
  const int t = threadIdx.x;

  for (int ps = 0; ps < 16; ++ps) {
    int e  = ps * 256 + t;
    int kk = e >> 6, nn = e & 63;
    Wl[kk * 72 + nn] = f2bf(W[(size_t)(bk * 64 + kk) * H_DIM + bn * 64 + nn]);
  }
  __syncthreads();
  for (int ps = 0; ps < 16; ++ps) {
    int o  = ps * 256 + t;
    int nl = o >> 6, kl = o & 63;
    int n  = bn * 64 + nl;
    int g  = kl >> 3, j = kl & 7;
    int ks = ((g ^ (n & 7)) << 3) | j;
    Wt[(size_t)p * (H_DIM * C_DIM) + (size_t)n * C_DIM + bk * 64 + kl] = Wl[ks * 72 + nl];
  }
}

// ---------------------------------------------------------------------------
// Kernel 2: FUSED QKV GEMM (unchanged — HBM-bound control).
// ---------------------------------------------------------------------------
__global__ __launch_bounds__(512, 1) void qkv_fused(
    const float* __restrict__ x, const u16* __restrict__ Wt,
    const float* __restrict__ bq, const float* __restrict__ bk, const float* __restrict__ bv,
    u16* __restrict__ qo, u16* __restrict__ ko, u16* __restrict__ vTo)
{
  __shared__ alignas(16) u16 SMEM[2][28672];   // 2 x (As 8KB | Bs 48KB) = 112 KB

  const int tid  = threadIdx.x;
  const int w    = tid >> 6, lane = tid & 63;
  const int t16  = lane & 15, quad = lane >> 4;
  const int mh   = w >> 2;        // m-half: rows mh*32..+32
  const int nq   = w & 3;         // n-strip: cols nq*96..+96
  const int rt   = blockIdx.x;    // 0..255 row tiles (64 rows each)

  f32x4 acc[2][6];
  for (int i = 0; i < 2; ++i)
    for (int j = 0; j < 6; ++j) acc[i][j] = f32x4{0.f, 0.f, 0.f, 0.f};

  const size_t rowBase = (size_t)rt * 64;
  const int arow = tid >> 3;      // 0..63
  const int ag   = tid & 7;       // 8-float granule
  const float* xrow = &x[(rowBase + arow) * C_DIM + ag * 8];

  float4 a0 = ((const float4*)(xrow))[0];
  float4 a1 = ((const float4*)(xrow))[1];
  {
    u16* As = SMEM[0];
    u16* Bs = SMEM[0] + 4096;
    for (int p = 0; p < 3; ++p) {
      const u16* Wp = Wt + (size_t)p * (H_DIM * C_DIM);
      for (int j = 0; j < 2; ++j) {
        int e8 = (((j << 3) + w) * 64 + lane) * 8;
        int rr = e8 >> 6, kk = e8 & 63;
        gload16(Wp + (size_t)rr * C_DIM + kk, &Bs[p * 8192 + e8]);
      }
    }
    u16x8 pk;
    pk[0] = f2bf(a0.x); pk[1] = f2bf(a0.y); pk[2] = f2bf(a0.z); pk[3] = f2bf(a0.w);
    pk[4] = f2bf(a1.x); pk[5] = f2bf(a1.y); pk[6] = f2bf(a1.z); pk[7] = f2bf(a1.w);
    *(u16x8*)&As[arow * 64 + ((ag ^ (arow & 7)) << 3)] = pk;
  }
  a0 = ((const float4*)(xrow + 64))[0];
  a1 = ((const float4*)(xrow + 64))[1];

  for (int it = 0; it < 32; ++it) {
    const int cur = it & 1, nxt = cur ^ 1;
    __syncthreads();

    if (it + 1 < 32) {
      const int k1 = (it + 1) * 64;
      u16* As = SMEM[nxt];
      u16* Bs = SMEM[nxt] + 4096;
      for (int p = 0; p < 3; ++p) {
        const u16* Wp = Wt + (size_t)p * (H_DIM * C_DIM);
        for (int j = 0; j < 2; ++j) {
          int e8 = (((j << 3) + w) * 64 + lane) * 8;
          int rr = e8 >> 6, kk = e8 & 63;
          gload16(Wp + (size_t)rr * C_DIM + k1 + kk, &Bs[p * 8192 + e8]);
        }
      }
      u16x8 pk;
      pk[0] = f2bf(a0.x); pk[1] = f2bf(a0.y); pk[2] = f2bf(a0.z); pk[3] = f2bf(a0.w);
      pk[4] = f2bf(a1.x); pk[5] = f2bf(a1.y); pk[6] = f2bf(a1.z); pk[7] = f2bf(a1.w);
      *(u16x8*)&As[arow * 64 + ((ag ^ (arow & 7)) << 3)] = pk;
      if (it + 2 < 32) {
        const float4* xp = (const float4*)(xrow + (it + 2) * 64);
        a0 = xp[0]; a1 = xp[1];
      }
    }

    u16* As = SMEM[cur];
    u16* Bs = SMEM[cur] + 4096;
    for (int ks = 0; ks < 2; ++ks) {
      bf16x8 af[2], bfr[6];
      for (int ra = 0; ra < 2; ++ra)
        af[ra] = *(const bf16x8*)&As[(mh * 32 + ra * 16 + t16) * 64 +
                                     (((ks * 4 + quad) ^ (t16 & 7)) << 3)];
      for (int c = 0; c < 6; ++c) {
        int col = nq * 96 + c * 16 + t16;
        int p = col >> 7, pc = col & 127;
        bfr[c] = *(const bf16x8*)&Bs[p * 8192 + pc * 64 +
                                     (((ks * 4 + quad) ^ (t16 & 7)) << 3)];
      }
      for (int ra = 0; ra < 2; ++ra)
        for (int c = 0; c < 6; ++c)
          acc[ra][c] = mfma_bf16(af[ra], bfr[c], acc[ra][c]);
    }
  }

  __syncthreads();
  u16* Oq = SMEM[0];            // 64 x 128 row-major swizzled
  u16* Ok = SMEM[0] + 8192;     // 64 x 128 row-major swizzled (== global layout)
  u16* Ov = SMEM[0] + 16384;    // 128 x 64 transposed swizzled (== global layout)

  for (int c = 0; c < 6; ++c) {
    int col = nq * 96 + c * 16 + t16;
    int p = col >> 7, pc = col & 127;
    float bias = (p == 0) ? bq[pc] : (p == 1) ? bk[pc] : bv[pc];
    for (int ra = 0; ra < 2; ++ra) {
      for (int r = 0; r < 4; ++r) {
        int row16 = mh * 32 + ra * 16 + quad * 4 + r;   // 0..63
        float v = acc[ra][c][r] + bias;
        if (p == 2) {
          int gt = row16 >> 3;
          Ov[pc * 64 + ((gt ^ (pc & 7)) << 3) + (row16 & 7)] = f2bf(v);
        } else {
          u16* O = (p == 0) ? Oq : Ok;
          int g = pc >> 3;
          O[row16 * 128 + (((g ^ (row16 & 15)) << 3) | (pc & 7))] = f2bf(v);
        }
      }
    }
  }
  __syncthreads();

  const int bb = rt >> 6;            // batch
  const int tb = (rt & 63) * 64;     // t offset within batch (one key-block)
  for (int ps = 0; ps < 2; ++ps) {
    int c = ps * 512 + tid;          // 16B chunk 0..1023
    {
      int row16 = c >> 4, g = c & 15;
      u16x8 v = *(const u16x8*)&Oq[row16 * 128 + ((g ^ (row16 & 15)) << 3)];
      *(u16x8*)&qo[(rowBase + row16) * H_DIM + g * 8] = v;
    }
    *(u16x8*)&ko[rowBase * H_DIM + c * 8] = *(const u16x8*)&Ok[c * 8];
    {
      int d = c >> 3, gc = c & 7;
      *(u16x8*)&vTo[((size_t)bb * H_DIM + d) * T_SEQ + tb + gc * 8] =
          *(const u16x8*)&Ov[c * 8];
    }
  }
}

// ---------------------------------------------------------------------------
// Kernel 3: causal flash attention — PROVEN 64-row shape (4 waves x 16 rows,
// ~140 VGPR, the 295.6us session's inner loop) + two additions:
//  (a) T5 setprio around both MFMA clusters (+4-7% measured on attn).
//  (b) balanced <=16-keytile split: nchunks(qt)=1+qt/16 in {1..4};
//      160 chunks/batch -> 640 blocks, max block 16 iters (old split: 32).
// Chunk 0 -> unnormalized fp32 into `out`; chunks >=1 -> Opart (fp32 if
// workspace allows else bf16). Mask-safe: kt0 = c*NT/n <= qt always.
// ---------------------------------------------------------------------------
__global__ __launch_bounds__(256, 2) void flash_attn(
    const u16* __restrict__ q, const u16* __restrict__ k,
    const u16* __restrict__ vT, float* __restrict__ out,
    void* __restrict__ OpartRaw, float* __restrict__ MLpart,
    int split, int pf32)
{
  __shared__ alignas(16) u16 Kt[2][64 * 128];    // 2 x 16 KB
  __shared__ alignas(16) u16 Vt[2][128 * 64];    // 2 x 16 KB
  __shared__ alignas(16) u16 Ps[4 * 16 * 72];    // 9 KB

  const int tid  = threadIdx.x;
  const int w    = tid >> 6, lane = tid & 63;
  const int t16  = lane & 15, quad = lane >> 4;
  const int b    = blockIdx.x;

  // ---- schedule: (qt, chunk) from blockIdx.y; long chunks dispatch first ----
  int qt, kt0, ktn, mls, esd;   // mls<0 => direct; esd==-2 => chunk0 -> out
  if (split) {
    const int j = blockIdx.y;   // 0..159
    int c, n;
    if (j < 64)       { qt = 63 - (j >> 2); c = j & 3; n = 4; }
    else if (j < 112) { int t = j - 64; int d3 = t / 3; qt = 47 - d3; c = t - d3 * 3; n = 3; }
    else if (j < 144) { int t = j - 112; qt = 31 - (t >> 1); c = t & 1; n = 2; }
    else              { qt = 159 - j; c = 0; n = 1; }
    const int NT = qt + 1;
    kt0 = c * NT / n;
    ktn = (c + 1) * NT / n - kt0;
    if (n == 1) { mls = -1; esd = -1; }
    else {
      int mlb, esb;
      if (qt >= 48)      { mlb = (qt - 48) * 4;       esb = (qt - 48) * 3; }
      else if (qt >= 32) { mlb = 64 + (qt - 32) * 3;  esb = 48 + (qt - 32) * 2; }
      else               { mlb = 112 + (qt - 16) * 2; esb = 80 + (qt - 16); }
      mls = b * 144 + mlb + c;
      esd = (c >= 1) ? (b * 96 + esb + c - 1) : -2;
    }
  } else {
    qt = 63 - blockIdx.y; kt0 = 0; ktn = qt + 1; mls = -1; esd = -1;
  }

  const float SCALE = 0.022097086912079612f;   // 2048^-0.5
  const float L2E   = 1.4426950408889634f;

  bf16x8 qf[4];
  {
    const u16* qrow = q + ((size_t)(b * T_SEQ + qt * 64 + w * 16 + t16)) * H_DIM;
    for (int c = 0; c < 4; ++c)
      qf[c] = *(const bf16x8*)(qrow + c * 32 + quad * 8);
  }

  f32x4 Oc[8];
  for (int i = 0; i < 8; ++i) Oc[i] = f32x4{0.f, 0.f, 0.f, 0.f};
  float mrow[4] = {-1e30f, -1e30f, -1e30f, -1e30f};
  float lrow[4] = {0.f, 0.f, 0.f, 0.f};

  const u16* kbase = k  + ((size_t)b * T_SEQ) * H_DIM;
  const u16* vbase = vT + ((size_t)b * H_DIM) * T_SEQ;

  // prefetch first tile into buffer 0
  {
    const u16* kg = kbase + (size_t)(kt0 * 64) * H_DIM;
    for (int j = 0; j < 4; ++j) {
      int e8 = (((j << 2) + w) * 64 + lane) * 8;
      gload16(kg + e8, &Kt[0][e8]);
      int d = e8 >> 6, kk = e8 & 63;
      gload16(vbase + (size_t)d * T_SEQ + kt0 * 64 + kk, &Vt[0][e8]);
    }
  }

  int cur = 0;
  for (int it = 0; it < ktn; ++it) {
    const int kt = kt0 + it;
    __syncthreads();   // drains prefetch of `cur`; WAR-guard for next prefetch
    if (it + 1 < ktn) {
      const int nb = cur ^ 1, kt1 = kt + 1;
      const u16* kg = kbase + (size_t)(kt1 * 64) * H_DIM;
      for (int j = 0; j < 4; ++j) {
        int e8 = (((j << 2) + w) * 64 + lane) * 8;
        gload16(kg + e8, &Kt[nb][e8]);
        int d = e8 >> 6, kk = e8 & 63;
        gload16(vbase + (size_t)d * T_SEQ + kt1 * 64 + kk, &Vt[nb][e8]);
      }
    }

    // S = Q K^T
    f32x4 S[4];
    for (int ct = 0; ct < 4; ++ct) S[ct] = f32x4{0.f, 0.f, 0.f, 0.f};
    __builtin_amdgcn_s_setprio(1);
    for (int c = 0; c < 4; ++c) {
      for (int ct = 0; ct < 4; ++ct) {
        bf16x8 kf = *(const bf16x8*)&Kt[cur][(ct * 16 + t16) * H_DIM +
                                            (((c * 4 + quad) ^ t16) << 3)];
        S[ct] = mfma_bf16(qf[c], kf, S[ct]);
      }
    }
    __builtin_amdgcn_s_setprio(0);

    const bool diag = (kt == qt);
    for (int ct = 0; ct < 4; ++ct)
      for (int r = 0; r < 4; ++r) {
        float s = S[ct][r] * SCALE;
        if (diag && (ct * 16 + t16 > w * 16 + quad * 4 + r)) s = -1e30f;
        S[ct][r] = s;
      }

    float alpha[4], mnew[4];
    for (int r = 0; r < 4; ++r) {
      float mx = red16_max(fmaxf(fmaxf(S[0][r], S[1][r]), fmaxf(S[2][r], S[3][r])));
      mnew[r]  = fmaxf(mrow[r], mx);
      alpha[r] = exp2f((mrow[r] - mnew[r]) * L2E);
      mrow[r]  = mnew[r];
    }
    for (int r = 0; r < 4; ++r) {
      float s = 0.f;
      for (int ct = 0; ct < 4; ++ct) {
        float pv = exp2f((S[ct][r] - mnew[r]) * L2E);
        S[ct][r] = pv;
        s += pv;
      }
      lrow[r] = lrow[r] * alpha[r] + red16_sum(s);
    }
    for (int dt = 0; dt < 8; ++dt)
      for (int r = 0; r < 4; ++r)
        Oc[dt][r] *= alpha[r];

    // P: C layout -> A layout via padded per-wave LDS scratch
    u16* pw = &Ps[w * 1152];
    for (int ct = 0; ct < 4; ++ct)
      for (int r = 0; r < 4; ++r)
        pw[(quad * 4 + r) * 72 + ct * 16 + t16] = f2bf(S[ct][r]);
    __asm__ volatile("s_waitcnt lgkmcnt(0)" ::: "memory");

    __builtin_amdgcn_s_setprio(1);
    for (int ks = 0; ks < 2; ++ks) {
      bf16x8 pf = *(const bf16x8*)&pw[t16 * 72 + ks * 32 + quad * 8];
      for (int dt = 0; dt < 8; ++dt) {
        bf16x8 vf = *(const bf16x8*)&Vt[cur][(dt * 16 + t16) * 64 +
                                            (((ks * 4 + quad) ^ (t16 & 7)) << 3)];
        Oc[dt] = mfma_bf16(pf, vf, Oc[dt]);
      }
    }
    __builtin_amdgcn_s_setprio(0);
    cur ^= 1;
  }

  if (mls < 0) {
    for (int r = 0; r < 4; ++r) {
      float inv = 1.0f / lrow[r];
      size_t row = (size_t)b * T_SEQ + qt * 64 + w * 16 + quad * 4 + r;
      for (int dt = 0; dt < 8; ++dt)
        out[row * H_DIM + dt * 16 + t16] = Oc[dt][r] * inv;
    }
  } else {
    if (t16 == 0)
      for (int r = 0; r < 4; ++r) {
        int row = w * 16 + quad * 4 + r;
        MLpart[(size_t)mls * 128 + row * 2 + 0] = mrow[r];
        MLpart[(size_t)mls * 128 + row * 2 + 1] = lrow[r];
      }
    if (esd == -2) {
      // chunk 0: unnormalized partial straight into out (combine rescales)
      for (int r = 0; r < 4; ++r) {
        size_t row = (size_t)b * T_SEQ + qt * 64 + w * 16 + quad * 4 + r;
        for (int dt = 0; dt < 8; ++dt)
          out[row * H_DIM + dt * 16 + t16] = Oc[dt][r];
      }
    } else if (pf32) {
      float* op = (float*)OpartRaw + (size_t)esd * 8192;
      for (int r = 0; r < 4; ++r) {
        int row = w * 16 + quad * 4 + r;
        for (int dt = 0; dt < 8; ++dt)
          op[row * 128 + dt * 16 + t16] = Oc[dt][r];
      }
    } else {
      u16* op = (u16*)OpartRaw + (size_t)esd * 8192;
      for (int r = 0; r < 4; ++r) {
        int row = w * 16 + quad * 4 + r;
        for (int dt = 0; dt < 8; ++dt)
          op[row * 128 + dt * 16 + t16] = f2bf(Oc[dt][r]);
      }
    }
  }
}

// ---------------------------------------------------------------------------
// Kernel 4: merge chunk 0 (in out, unnormalized fp32) with chunks 1..n-1
// (Opart, fp32 or bf16). One block per split (b,qt); n in {2,3,4}.
// ---------------------------------------------------------------------------
__global__ __launch_bounds__(256) void combine(
    const void* __restrict__ OpartRaw, const float* __restrict__ MLpart,
    float* __restrict__ out, int pf32)
{
  __shared__ float cs[4][64];
  const float L2E = 1.4426950408889634f;
  const int s = blockIdx.x;            // 0..191
  const int b = s / 48, qt = 16 + (s % 48);
  const int t = threadIdx.x;

  int n, mlb, esb;
  if (qt >= 48)      { n = 4; mlb = (qt - 48) * 4;       esb = (qt - 48) * 3; }
  else if (qt >= 32) { n = 3; mlb = 64 + (qt - 32) * 3;  esb = 48 + (qt - 32) * 2; }
  else               { n = 2; mlb = 112 + (qt - 16) * 2; esb = 80 + (qt - 16); }
  const int mls0 = b * 144 + mlb;
  const int esd0 = b * 96 + esb;

  if (t < 64) {
    float m[4], l[4];
    float mg = -1e30f;
    for (int c = 0; c < n; ++c) {
      const float* ML = MLpart + (size_t)(mls0 + c) * 128;
      m[c] = ML[t * 2]; l[c] = ML[t * 2 + 1];
      mg = fmaxf(mg, m[c]);
    }
    float denom = 0.f, e[4];
    for (int c = 0; c < n; ++c) {
      e[c] = exp2f((m[c] - mg) * L2E);
      denom += l[c] * e[c];
    }
    float inv = 1.0f / denom;
    for (int c = 0; c < n; ++c) cs[c][t] = e[c] * inv;
  }
  __syncthreads();

  float* o = out + ((size_t)b * T_SEQ + (size_t)qt * 64) * (size_t)H_DIM;
  for (int i4 = t; i4 < 2048; i4 += 256) {       // float4 chunks, 32 per row
    const int row = i4 >> 5;
    float4 acc = ((float4*)o)[i4];
    const float c0 = cs[0][row];
    acc.x *= c0; acc.y *= c0; acc.z *= c0; acc.w *= c0;
    for (int c = 1; c < n; ++c) {
      const float cc = cs[c][row];
      if (pf32) {
        const float4 p = ((const float4*)((const float*)OpartRaw +
                          (size_t)(esd0 + c - 1) * 8192))[i4];
        acc.x += p.x * cc; acc.y += p.y * cc;
        acc.z += p.z * cc; acc.w += p.w * cc;
      } else {
        const u16x4 p = ((const u16x4*)((const u16*)OpartRaw +
                         (size_t)(esd0 + c - 1) * 8192))[i4];
        acc.x += bf2f(p[0]) * cc; acc.y += bf2f(p[1]) * cc;
        acc.z += bf2f(p[2]) * cc; acc.w += bf2f(p[3]) * cc;
      }
    }
    ((float4*)o)[i4] = acc;
  }
}

// ---------------------------------------------------------------------------
extern "C" void kernel_launch(void* const* d_in, const int* in_sizes, int n_in,
                              void* d_out, int out_size, void* d_ws, size_t ws_size,
                              hipStream_t stream) {
  const float* x  = (const float*)d_in[0];
  const float* Wk = (const float*)d_in[1];
  const float* bk = (const float*)d_in[2];
  const float* Wq = (const float*)d_in[3];
  const float* bq = (const float*)d_in[4];
  const float* Wv = (const float*)d_in[5];
  const float* bv = (const float*)d_in[6];
  float* out = (float*)d_out;

  char* ws = (char*)d_ws;
  u16* qb  = (u16*)(ws);                       // 4 MB  [b][t][128] bf16
  u16* kb  = (u16*)(ws + 4194304);             // 4 MB  [b][t][d'] bf16 (swizzled)
  u16* vT  = (u16*)(ws + 8388608);             // 4 MB  [b][128][t'] bf16 (swizzled)
  u16* Wt  = (u16*)(ws + 12582912);            // 1.5 MB pre-swizzled weights
  void* Opart = (void*)(ws + 14155776);        // partials: 384 slots of 64x128

  const size_t base     = 14155776ull;
  const size_t ml_bytes = 294912ull;           // 576 slots x 128 f32
  const size_t need_f32 = base + 12582912ull + ml_bytes;   // fp32 partials
  const size_t need_b16 = base + 6291456ull  + ml_bytes;   // bf16 partials

  int split, pf32;
  float* MLpart;
  if (ws_size >= need_f32) {
    split = 1; pf32 = 1;
    MLpart = (float*)(ws + base + 12582912ull);
  } else if (ws_size >= need_b16) {
    split = 1; pf32 = 0;
    MLpart = (float*)(ws + base + 6291456ull);
  } else {
    split = 0; pf32 = 0;
    MLpart = (float*)(ws + base);              // unused
  }

  hipLaunchKernelGGL(transpose_w, dim3(32, 2, 3), dim3(256), 0, stream, Wq, Wk, Wv, Wt);
  hipLaunchKernelGGL(qkv_fused, dim3(256), dim3(512), 0, stream,
                     x, Wt, bq, bk, bv, qb, kb, vT);
  hipLaunchKernelGGL(flash_attn, dim3(4, split ? 160 : 64), dim3(256), 0, stream,
                     qb, kb, vT, out, Opart, MLpart, split, pf32);
  if (split)
    hipLaunchKernelGGL(combine, dim3(192), dim3(256), 0, stream, Opart, MLpart, out, pf32);
}

// Round 7
// 295.783 us; speedup vs baseline: 1.0541x; 1.0113x over previous
//
#include <hip/hip_runtime.h>
#include <hip/hip_bf16.h>
#include <stdint.h>

#define T_SEQ 4096
#define C_DIM 2048
#define H_DIM 128
#define NBATCH 4

typedef unsigned short u16;
typedef __attribute__((ext_vector_type(8))) __bf16 bf16x8;
typedef __attribute__((ext_vector_type(4))) float f32x4;
typedef __attribute__((ext_vector_type(8))) unsigned short u16x8;
typedef __attribute__((ext_vector_type(4))) unsigned short u16x4;

__device__ __forceinline__ u16 f2bf(float f) {
  union { float f; uint32_t i; } v; v.f = f;
  uint32_t r = v.i + 0x7FFFu + ((v.i >> 16) & 1u);
  return (u16)(r >> 16);
}
__device__ __forceinline__ float bf2f(u16 u) {
  union { uint32_t i; float f; } v; v.i = ((uint32_t)u) << 16;
  return v.f;
}

__device__ __forceinline__ void gload16(const void* g, void* l) {
  __builtin_amdgcn_global_load_lds(
      (__attribute__((address_space(1))) void*)(g),
      (__attribute__((address_space(3))) void*)(l), 16, 0, 0);
}

__device__ __forceinline__ f32x4 mfma_bf16(bf16x8 a, bf16x8 b, f32x4 c) {
  return __builtin_amdgcn_mfma_f32_16x16x32_bf16(a, b, c, 0, 0, 0);
}

// DPP row rotate (16-lane row) reductions — no LDS traffic.
template<int CTRL>
__device__ __forceinline__ float dpp_mov(float x) {
  return __int_as_float(__builtin_amdgcn_mov_dpp(__float_as_int(x), CTRL, 0xF, 0xF, true));
}
__device__ __forceinline__ float red16_max(float v) {
  v = fmaxf(v, dpp_mov<0x121>(v));
  v = fmaxf(v, dpp_mov<0x122>(v));
  v = fmaxf(v, dpp_mov<0x124>(v));
  v = fmaxf(v, dpp_mov<0x128>(v));
  return v;
}
__device__ __forceinline__ float red16_sum(float v) {
  v += dpp_mov<0x121>(v);
  v += dpp_mov<0x122>(v);
  v += dpp_mov<0x124>(v);
  v += dpp_mov<0x128>(v);
  return v;
}

// ---------------------------------------------------------------------------
// Kernel 1: W fp32 [2048][128] -> Wt bf16 [p][n][k], pre-swizzled so that
// contiguous global_load_lds staging lands an XOR-swizzled B-tile in LDS.
// (unchanged, session-verified)
// ---------------------------------------------------------------------------
__global__ __launch_bounds__(256) void transpose_w(
    const float* __restrict__ Wq, const float* __restrict__ Wk,
    const float* __restrict__ Wv, u16* __restrict__ Wt)
{
  __shared__ u16 Wl[64 * 72];
  const int bk = blockIdx.x;   // k-tile 0..31
  const int bn = blockIdx.y;   // n-tile 0..1
  const int p  = blockIdx.z;   // 0 q, 1 k, 2 v
  const float* W = (p == 0) ? Wq : (p == 1) ? Wk : Wv;
  const int t = threadIdx.x;

  for (int ps = 0; ps < 16; ++ps) {
    int e  = ps * 256 + t;
    int kk = e >> 6, nn = e & 63;
    Wl[kk * 72 + nn] = f2bf(W[(size_t)(bk * 64 + kk) * H_DIM + bn * 64 + nn]);
  }
  __syncthreads();
  for (int ps = 0; ps < 16; ++ps) {
    int o  = ps * 256 + t;
    int nl = o >> 6, kl = o & 63;
    int n  = bn * 64 + nl;
    int g  = kl >> 3, j = kl & 7;
    int ks = ((g ^ (n & 7)) << 3) | j;
    Wt[(size_t)p * (H_DIM * C_DIM) + (size_t)n * C_DIM + bk * 64 + kl] = Wl[ks * 72 + nl];
  }
}

// ---------------------------------------------------------------------------
// Kernel 2: FUSED QKV GEMM. ONE change this round: the q-output (p==0) is
// pre-multiplied by SCALE=2048^-0.5 in the epilogue, so flash_attn never
// scales logits (removes 16 fmul/iter/thread there at zero cost here).
// ---------------------------------------------------------------------------
__global__ __launch_bounds__(512, 1) void qkv_fused(
    const float* __restrict__ x, const u16* __restrict__ Wt,
    const float* __restrict__ bq, const float* __restrict__ bk, const float* __restrict__ bv,
    u16* __restrict__ qo, u16* __restrict__ ko, u16* __restrict__ vTo)
{
  __shared__ alignas(16) u16 SMEM[2][28672];   // 2 x (As 8KB | Bs 48KB) = 112 KB

  const int tid  = threadIdx.x;
  const int w    = tid >> 6, lane = tid & 63;
  const int t16  = lane & 15, quad = lane >> 4;
  const int mh   = w >> 2;        // m-half: rows mh*32..+32
  const int nq   = w & 3;         // n-strip: cols nq*96..+96
  const int rt   = blockIdx.x;    // 0..255 row tiles (64 rows each)

  f32x4 acc[2][6];
  for (int i = 0; i < 2; ++i)
    for (int j = 0; j < 6; ++j) acc[i][j] = f32x4{0.f, 0.f, 0.f, 0.f};

  const size_t rowBase = (size_t)rt * 64;
  const int arow = tid >> 3;      // 0..63
  const int ag   = tid & 7;       // 8-float granule
  const float* xrow = &x[(rowBase + arow) * C_DIM + ag * 8];

  float4 a0 = ((const float4*)(xrow))[0];
  float4 a1 = ((const float4*)(xrow))[1];
  {
    u16* As = SMEM[0];
    u16* Bs = SMEM[0] + 4096;
    for (int p = 0; p < 3; ++p) {
      const u16* Wp = Wt + (size_t)p * (H_DIM * C_DIM);
      for (int j = 0; j < 2; ++j) {
        int e8 = (((j << 3) + w) * 64 + lane) * 8;
        int rr = e8 >> 6, kk = e8 & 63;
        gload16(Wp + (size_t)rr * C_DIM + kk, &Bs[p * 8192 + e8]);
      }
    }
    u16x8 pk;
    pk[0] = f2bf(a0.x); pk[1] = f2bf(a0.y); pk[2] = f2bf(a0.z); pk[3] = f2bf(a0.w);
    pk[4] = f2bf(a1.x); pk[5] = f2bf(a1.y); pk[6] = f2bf(a1.z); pk[7] = f2bf(a1.w);
    *(u16x8*)&As[arow * 64 + ((ag ^ (arow & 7)) << 3)] = pk;
  }
  a0 = ((const float4*)(xrow + 64))[0];
  a1 = ((const float4*)(xrow + 64))[1];

  for (int it = 0; it < 32; ++it) {
    const int cur = it & 1, nxt = cur ^ 1;
    __syncthreads();

    if (it + 1 < 32) {
      const int k1 = (it + 1) * 64;
      u16* As = SMEM[nxt];
      u16* Bs = SMEM[nxt] + 4096;
      for (int p = 0; p < 3; ++p) {
        const u16* Wp = Wt + (size_t)p * (H_DIM * C_DIM);
        for (int j = 0; j < 2; ++j) {
          int e8 = (((j << 3) + w) * 64 + lane) * 8;
          int rr = e8 >> 6, kk = e8 & 63;
          gload16(Wp + (size_t)rr * C_DIM + k1 + kk, &Bs[p * 8192 + e8]);
        }
      }
      u16x8 pk;
      pk[0] = f2bf(a0.x); pk[1] = f2bf(a0.y); pk[2] = f2bf(a0.z); pk[3] = f2bf(a0.w);
      pk[4] = f2bf(a1.x); pk[5] = f2bf(a1.y); pk[6] = f2bf(a1.z); pk[7] = f2bf(a1.w);
      *(u16x8*)&As[arow * 64 + ((ag ^ (arow & 7)) << 3)] = pk;
      if (it + 2 < 32) {
        const float4* xp = (const float4*)(xrow + (it + 2) * 64);
        a0 = xp[0]; a1 = xp[1];
      }
    }

    u16* As = SMEM[cur];
    u16* Bs = SMEM[cur] + 4096;
    for (int ks = 0; ks < 2; ++ks) {
      bf16x8 af[2], bfr[6];
      for (int ra = 0; ra < 2; ++ra)
        af[ra] = *(const bf16x8*)&As[(mh * 32 + ra * 16 + t16) * 64 +
                                     (((ks * 4 + quad) ^ (t16 & 7)) << 3)];
      for (int c = 0; c < 6; ++c) {
        int col = nq * 96 + c * 16 + t16;
        int p = col >> 7, pc = col & 127;
        bfr[c] = *(const bf16x8*)&Bs[p * 8192 + pc * 64 +
                                     (((ks * 4 + quad) ^ (t16 & 7)) << 3)];
      }
      for (int ra = 0; ra < 2; ++ra)
        for (int c = 0; c < 6; ++c)
          acc[ra][c] = mfma_bf16(af[ra], bfr[c], acc[ra][c]);
    }
  }

  __syncthreads();
  u16* Oq = SMEM[0];            // 64 x 128 row-major swizzled
  u16* Ok = SMEM[0] + 8192;     // 64 x 128 row-major swizzled (== global layout)
  u16* Ov = SMEM[0] + 16384;    // 128 x 64 transposed swizzled (== global layout)

  const float QSCALE = 0.022097086912079612f;   // 2048^-0.5 folded into q
  for (int c = 0; c < 6; ++c) {
    int col = nq * 96 + c * 16 + t16;
    int p = col >> 7, pc = col & 127;
    float bias = (p == 0) ? bq[pc] : (p == 1) ? bk[pc] : bv[pc];
    for (int ra = 0; ra < 2; ++ra) {
      for (int r = 0; r < 4; ++r) {
        int row16 = mh * 32 + ra * 16 + quad * 4 + r;   // 0..63
        float v = acc[ra][c][r] + bias;
        if (p == 0) v *= QSCALE;
        if (p == 2) {
          int gt = row16 >> 3;
          Ov[pc * 64 + ((gt ^ (pc & 7)) << 3) + (row16 & 7)] = f2bf(v);
        } else {
          u16* O = (p == 0) ? Oq : Ok;
          int g = pc >> 3;
          O[row16 * 128 + (((g ^ (row16 & 15)) << 3) | (pc & 7))] = f2bf(v);
        }
      }
    }
  }
  __syncthreads();

  const int bb = rt >> 6;            // batch
  const int tb = (rt & 63) * 64;     // t offset within batch (one key-block)
  for (int ps = 0; ps < 2; ++ps) {
    int c = ps * 512 + tid;          // 16B chunk 0..1023
    {
      int row16 = c >> 4, g = c & 15;
      u16x8 v = *(const u16x8*)&Oq[row16 * 128 + ((g ^ (row16 & 15)) << 3)];
      *(u16x8*)&qo[(rowBase + row16) * H_DIM + g * 8] = v;
    }
    *(u16x8*)&ko[rowBase * H_DIM + c * 8] = *(const u16x8*)&Ok[c * 8];
    {
      int d = c >> 3, gc = c & 7;
      *(u16x8*)&vTo[((size_t)bb * H_DIM + d) * T_SEQ + tb + gc * 8] =
          *(const u16x8*)&Ov[c * 8];
    }
  }
}

// ---------------------------------------------------------------------------
// Kernel 3: causal flash attention — measured 64-row shape (Round-6, 299us)
// with TWO softmax-VALU cuts this round:
//  (a) logits arrive pre-scaled (q folded) — no SCALE mul per element.
//  (b) T13 defer-max THR=8: skip m-update/alpha/O-rescale when tile max
//      grows <= 8 nat-log units (P bounded by e^8, bf16-safe; HK-verified).
// Split/epilogue/combine structure unchanged from the measured kernel.
// ---------------------------------------------------------------------------
__global__ __launch_bounds__(256, 2) void flash_attn(
    const u16* __restrict__ q, const u16* __restrict__ k,
    const u16* __restrict__ vT, float* __restrict__ out,
    void* __restrict__ OpartRaw, float* __restrict__ MLpart,
    int split, int pf32)
{
  __shared__ alignas(16) u16 Kt[2][64 * 128];    // 2 x 16 KB
  __shared__ alignas(16) u16 Vt[2][128 * 64];    // 2 x 16 KB
  __shared__ alignas(16) u16 Ps[4 * 16 * 72];    // 9 KB

  const int tid  = threadIdx.x;
  const int w    = tid >> 6, lane = tid & 63;
  const int t16  = lane & 15, quad = lane >> 4;
  const int b    = blockIdx.x;

  // ---- schedule: (qt, chunk) from blockIdx.y; long chunks dispatch first ----
  int qt, kt0, ktn, mls, esd;   // mls<0 => direct; esd==-2 => chunk0 -> out
  if (split) {
    const int j = blockIdx.y;   // 0..159
    int c, n;
    if (j < 64)       { qt = 63 - (j >> 2); c = j & 3; n = 4; }
    else if (j < 112) { int t = j - 64; int d3 = t / 3; qt = 47 - d3; c = t - d3 * 3; n = 3; }
    else if (j < 144) { int t = j - 112; qt = 31 - (t >> 1); c = t & 1; n = 2; }
    else              { qt = 159 - j; c = 0; n = 1; }
    const int NT = qt + 1;
    kt0 = c * NT / n;
    ktn = (c + 1) * NT / n - kt0;
    if (n == 1) { mls = -1; esd = -1; }
    else {
      int mlb, esb;
      if (qt >= 48)      { mlb = (qt - 48) * 4;       esb = (qt - 48) * 3; }
      else if (qt >= 32) { mlb = 64 + (qt - 32) * 3;  esb = 48 + (qt - 32) * 2; }
      else               { mlb = 112 + (qt - 16) * 2; esb = 80 + (qt - 16); }
      mls = b * 144 + mlb + c;
      esd = (c >= 1) ? (b * 96 + esb + c - 1) : -2;
    }
  } else {
    qt = 63 - blockIdx.y; kt0 = 0; ktn = qt + 1; mls = -1; esd = -1;
  }

  const float L2E = 1.4426950408889634f;

  bf16x8 qf[4];
  {
    const u16* qrow = q + ((size_t)(b * T_SEQ + qt * 64 + w * 16 + t16)) * H_DIM;
    for (int c = 0; c < 4; ++c)
      qf[c] = *(const bf16x8*)(qrow + c * 32 + quad * 8);
  }

  f32x4 Oc[8];
  for (int i = 0; i < 8; ++i) Oc[i] = f32x4{0.f, 0.f, 0.f, 0.f};
  float mrow[4] = {-1e30f, -1e30f, -1e30f, -1e30f};
  float lrow[4] = {0.f, 0.f, 0.f, 0.f};

  const u16* kbase = k  + ((size_t)b * T_SEQ) * H_DIM;
  const u16* vbase = vT + ((size_t)b * H_DIM) * T_SEQ;

  // prefetch first tile into buffer 0
  {
    const u16* kg = kbase + (size_t)(kt0 * 64) * H_DIM;
    for (int j = 0; j < 4; ++j) {
      int e8 = (((j << 2) + w) * 64 + lane) * 8;
      gload16(kg + e8, &Kt[0][e8]);
      int d = e8 >> 6, kk = e8 & 63;
      gload16(vbase + (size_t)d * T_SEQ + kt0 * 64 + kk, &Vt[0][e8]);
    }
  }

  int cur = 0;
  for (int it = 0; it < ktn; ++it) {
    const int kt = kt0 + it;
    __syncthreads();   // drains prefetch of `cur`; WAR-guard for next prefetch
    if (it + 1 < ktn) {
      const int nb = cur ^ 1, kt1 = kt + 1;
      const u16* kg = kbase + (size_t)(kt1 * 64) * H_DIM;
      for (int j = 0; j < 4; ++j) {
        int e8 = (((j << 2) + w) * 64 + lane) * 8;
        gload16(kg + e8, &Kt[nb][e8]);
        int d = e8 >> 6, kk = e8 & 63;
        gload16(vbase + (size_t)d * T_SEQ + kt1 * 64 + kk, &Vt[nb][e8]);
      }
    }

    // S = Q K^T  (logits pre-scaled via q)
    f32x4 S[4];
    for (int ct = 0; ct < 4; ++ct) S[ct] = f32x4{0.f, 0.f, 0.f, 0.f};
    __builtin_amdgcn_s_setprio(1);
    for (int c = 0; c < 4; ++c) {
      for (int ct = 0; ct < 4; ++ct) {
        bf16x8 kf = *(const bf16x8*)&Kt[cur][(ct * 16 + t16) * H_DIM +
                                            (((c * 4 + quad) ^ t16) << 3)];
        S[ct] = mfma_bf16(qf[c], kf, S[ct]);
      }
    }
    __builtin_amdgcn_s_setprio(0);

    if (kt == qt) {   // diagonal tile: causal mask
      for (int ct = 0; ct < 4; ++ct)
        for (int r = 0; r < 4; ++r)
          if (ct * 16 + t16 > w * 16 + quad * 4 + r) S[ct][r] = -1e30f;
    }

    // defer-max online softmax (T13, THR=8 nat-log)
    float alpha[4];
    bool any = false;
    for (int r = 0; r < 4; ++r) {
      float mx = red16_max(fmaxf(fmaxf(S[0][r], S[1][r]), fmaxf(S[2][r], S[3][r])));
      if (mx > mrow[r] + 8.0f) {
        alpha[r] = exp2f((mrow[r] - mx) * L2E);
        mrow[r] = mx;
        any = true;
      } else {
        alpha[r] = 1.0f;
      }
    }
    if (any) {
      for (int r = 0; r < 4; ++r) lrow[r] *= alpha[r];
      for (int dt = 0; dt < 8; ++dt)
        for (int r = 0; r < 4; ++r)
          Oc[dt][r] *= alpha[r];
    }
    for (int r = 0; r < 4; ++r) {
      float s = 0.f;
      for (int ct = 0; ct < 4; ++ct) {
        float pv = exp2f((S[ct][r] - mrow[r]) * L2E);
        S[ct][r] = pv;
        s += pv;
      }
      lrow[r] += red16_sum(s);
    }

    // P: C layout -> A layout via padded per-wave LDS scratch
    u16* pw = &Ps[w * 1152];
    for (int ct = 0; ct < 4; ++ct)
      for (int r = 0; r < 4; ++r)
        pw[(quad * 4 + r) * 72 + ct * 16 + t16] = f2bf(S[ct][r]);
    __asm__ volatile("s_waitcnt lgkmcnt(0)" ::: "memory");

    __builtin_amdgcn_s_setprio(1);
    for (int ks = 0; ks < 2; ++ks) {
      bf16x8 pf = *(const bf16x8*)&pw[t16 * 72 + ks * 32 + quad * 8];
      for (int dt = 0; dt < 8; ++dt) {
        bf16x8 vf = *(const bf16x8*)&Vt[cur][(dt * 16 + t16) * 64 +
                                            (((ks * 4 + quad) ^ (t16 & 7)) << 3)];
        Oc[dt] = mfma_bf16(pf, vf, Oc[dt]);
      }
    }
    __builtin_amdgcn_s_setprio(0);
    cur ^= 1;
  }

  if (mls < 0) {
    for (int r = 0; r < 4; ++r) {
      float inv = 1.0f / lrow[r];
      size_t row = (size_t)b * T_SEQ + qt * 64 + w * 16 + quad * 4 + r;
      for (int dt = 0; dt < 8; ++dt)
        out[row * H_DIM + dt * 16 + t16] = Oc[dt][r] * inv;
    }
  } else {
    if (t16 == 0)
      for (int r = 0; r < 4; ++r) {
        int row = w * 16 + quad * 4 + r;
        MLpart[(size_t)mls * 128 + row * 2 + 0] = mrow[r];
        MLpart[(size_t)mls * 128 + row * 2 + 1] = lrow[r];
      }
    if (esd == -2) {
      // chunk 0: unnormalized partial straight into out (combine rescales)
      for (int r = 0; r < 4; ++r) {
        size_t row = (size_t)b * T_SEQ + qt * 64 + w * 16 + quad * 4 + r;
        for (int dt = 0; dt < 8; ++dt)
          out[row * H_DIM + dt * 16 + t16] = Oc[dt][r];
      }
    } else if (pf32) {
      float* op = (float*)OpartRaw + (size_t)esd * 8192;
      for (int r = 0; r < 4; ++r) {
        int row = w * 16 + quad * 4 + r;
        for (int dt = 0; dt < 8; ++dt)
          op[row * 128 + dt * 16 + t16] = Oc[dt][r];
      }
    } else {
      u16* op = (u16*)OpartRaw + (size_t)esd * 8192;
      for (int r = 0; r < 4; ++r) {
        int row = w * 16 + quad * 4 + r;
        for (int dt = 0; dt < 8; ++dt)
          op[row * 128 + dt * 16 + t16] = f2bf(Oc[dt][r]);
      }
    }
  }
}

// ---------------------------------------------------------------------------
// Kernel 4: merge chunk 0 (in out, unnormalized fp32) with chunks 1..n-1
// (Opart, fp32 or bf16). One block per split (b,qt); n in {2,3,4}.
// ---------------------------------------------------------------------------
__global__ __launch_bounds__(256) void combine(
    const void* __restrict__ OpartRaw, const float* __restrict__ MLpart,
    float* __restrict__ out, int pf32)
{
  __shared__ float cs[4][64];
  const float L2E = 1.4426950408889634f;
  const int s = blockIdx.x;            // 0..191
  const int b = s / 48, qt = 16 + (s % 48);
  const int t = threadIdx.x;

  int n, mlb, esb;
  if (qt >= 48)      { n = 4; mlb = (qt - 48) * 4;       esb = (qt - 48) * 3; }
  else if (qt >= 32) { n = 3; mlb = 64 + (qt - 32) * 3;  esb = 48 + (qt - 32) * 2; }
  else               { n = 2; mlb = 112 + (qt - 16) * 2; esb = 80 + (qt - 16); }
  const int mls0 = b * 144 + mlb;
  const int esd0 = b * 96 + esb;

  if (t < 64) {
    float m[4], l[4];
    float mg = -1e30f;
    for (int c = 0; c < n; ++c) {
      const float* ML = MLpart + (size_t)(mls0 + c) * 128;
      m[c] = ML[t * 2]; l[c] = ML[t * 2 + 1];
      mg = fmaxf(mg, m[c]);
    }
    float denom = 0.f, e[4];
    for (int c = 0; c < n; ++c) {
      e[c] = exp2f((m[c] - mg) * L2E);
      denom += l[c] * e[c];
    }
    float inv = 1.0f / denom;
    for (int c = 0; c < n; ++c) cs[c][t] = e[c] * inv;
  }
  __syncthreads();

  float* o = out + ((size_t)b * T_SEQ + (size_t)qt * 64) * (size_t)H_DIM;
  for (int i4 = t; i4 < 2048; i4 += 256) {       // float4 chunks, 32 per row
    const int row = i4 >> 5;
    float4 acc = ((float4*)o)[i4];
    const float c0 = cs[0][row];
    acc.x *= c0; acc.y *= c0; acc.z *= c0; acc.w *= c0;
    for (int c = 1; c < n; ++c) {
      const float cc = cs[c][row];
      if (pf32) {
        const float4 p = ((const float4*)((const float*)OpartRaw +
                          (size_t)(esd0 + c - 1) * 8192))[i4];
        acc.x += p.x * cc; acc.y += p.y * cc;
        acc.z += p.z * cc; acc.w += p.w * cc;
      } else {
        const u16x4 p = ((const u16x4*)((const u16*)OpartRaw +
                         (size_t)(esd0 + c - 1) * 8192))[i4];
        acc.x += bf2f(p[0]) * cc; acc.y += bf2f(p[1]) * cc;
        acc.z += bf2f(p[2]) * cc; acc.w += bf2f(p[3]) * cc;
      }
    }
    ((float4*)o)[i4] = acc;
  }
}

// ---------------------------------------------------------------------------
extern "C" void kernel_launch(void* const* d_in, const int* in_sizes, int n_in,
                              void* d_out, int out_size, void* d_ws, size_t ws_size,
                              hipStream_t stream) {
  const float* x  = (const float*)d_in[0];
  const float* Wk = (const float*)d_in[1];
  const float* bk = (const float*)d_in[2];
  const float* Wq = (const float*)d_in[3];
  const float* bq = (const float*)d_in[4];
  const float* Wv = (const float*)d_in[5];
  const float* bv = (const float*)d_in[6];
  float* out = (float*)d_out;

  char* ws = (char*)d_ws;
  u16* qb  = (u16*)(ws);                       // 4 MB  [b][t][128] bf16 (pre-scaled)
  u16* kb  = (u16*)(ws + 4194304);             // 4 MB  [b][t][d'] bf16 (swizzled)
  u16* vT  = (u16*)(ws + 8388608);             // 4 MB  [b][128][t'] bf16 (swizzled)
  u16* Wt  = (u16*)(ws + 12582912);            // 1.5 MB pre-swizzled weights
  void* Opart = (void*)(ws + 14155776);        // partials: 384 slots of 64x128

  const size_t base     = 14155776ull;
  const size_t ml_bytes = 294912ull;           // 576 slots x 128 f32
  const size_t need_f32 = base + 12582912ull + ml_bytes;   // fp32 partials
  const size_t need_b16 = base + 6291456ull  + ml_bytes;   // bf16 partials

  int split, pf32;
  float* MLpart;
  if (ws_size >= need_f32) {
    split = 1; pf32 = 1;
    MLpart = (float*)(ws + base + 12582912ull);
  } else if (ws_size >= need_b16) {
    split = 1; pf32 = 0;
    MLpart = (float*)(ws + base + 6291456ull);
  } else {
    split = 0; pf32 = 0;
    MLpart = (float*)(ws + base);              // unused
  }

  hipLaunchKernelGGL(transpose_w, dim3(32, 2, 3), dim3(256), 0, stream, Wq, Wk, Wv, Wt);
  hipLaunchKernelGGL(qkv_fused, dim3(256), dim3(512), 0, stream,
                     x, Wt, bq, bk, bv, qb, kb, vT);
  hipLaunchKernelGGL(flash_attn, dim3(4, split ? 160 : 64), dim3(256), 0, stream,
                     qb, kb, vT, out, Opart, MLpart, split, pf32);
  if (split)
    hipLaunchKernelGGL(combine, dim3(192), dim3(256), 0, stream, Opart, MLpart, out, pf32);
}